// Round 7
// baseline (158.293 us; speedup 1.0000x reference)
//
#include <hip/hip_runtime.h>
#include <hip/hip_bf16.h>
#include <stdint.h>

#define M_ROWS 8192
#define K_IN   2048
#define KB4    (K_IN / 2)          // packed fp4 bytes per row = 1024
#define N_OUT  2048

typedef int   v4i   __attribute__((ext_vector_type(4)));
typedef int   v8i   __attribute__((ext_vector_type(8)));
typedef float f32x4 __attribute__((ext_vector_type(4)));

// ---------------------------------------------------------------------------
// async global->LDS, 16B per lane. LDS dest = wave-uniform base + lane*16.
__device__ __forceinline__ void load_lds16(const void* g, void* l) {
    __builtin_amdgcn_global_load_lds(
        (const __attribute__((address_space(1))) uint32_t*)g,
        (__attribute__((address_space(3))) uint32_t*)l,
        16, 0, 0);
}

// fp4 e2m1 RNE quantization of v. Levels: 0,0.5,1,1.5,2,3,4,6.
__device__ __forceinline__ uint32_t fp4_e2m1(float v) {
    float m = fabsf(v);
    uint32_t s = (v < 0.f) ? 0x8u : 0x0u;
    uint32_t c;
    if      (m < 0.25f) c = 0;
    else if (m < 0.75f) c = 1;
    else if (m < 1.25f) c = 2;
    else if (m < 1.75f) c = 3;
    else if (m < 2.50f) c = 4;
    else if (m < 3.50f) c = 5;
    else if (m < 5.00f) c = 6;
    else                c = 7;
    return (c == 0) ? 0u : (s | c);
}

// ---------------------------------------------------------------------------
// Quantization. One wave per row, no barriers.
// Waves [0, M_ROWS): input rows -> per-row absmax + sign(x) as packed fp4,
//   ROW-MAJOR Aq[m][KB4] (+1 -> 0x2, -1 -> 0xA, 0 -> 0x0, elem 2i low nib).
// Waves [M_ROWS, +N_OUT): weight rows -> e2m1(sign(w)/gamma) written
//   CHUNK-TRANSPOSED: Wqt[c][n][16B], c = k/32 (lane L handles chunk L).
__global__ __launch_bounds__(256) void quant_rows(
    const float* __restrict__ in, const float* __restrict__ w,
    const float* __restrict__ gamma,
    uint8_t* __restrict__ aq, uint8_t* __restrict__ wqt,
    float* __restrict__ scale)
{
    const int lane = threadIdx.x & 63;
    const int wv   = threadIdx.x >> 6;
    const int gw   = blockIdx.x * 4 + wv;          // global wave id = row id

    if (gw < M_ROWS) {
        const float4* rp = (const float4*)(in + (size_t)gw * K_IN);
        uint16_t* op = (uint16_t*)(aq + (size_t)gw * KB4);
        float m = 0.f;
        #pragma unroll
        for (int j = 0; j < 8; j++) {
            float4 x = rp[j * 64 + lane];
            float xs[4] = {x.x, x.y, x.z, x.w};
            uint32_t pk = 0;
            #pragma unroll
            for (int c = 0; c < 4; c++) {
                m = fmaxf(m, fabsf(xs[c]));
                uint32_t n = (xs[c] > 0.f) ? 0x2u : ((xs[c] < 0.f) ? 0xAu : 0u);
                pk |= n << (4 * c);
            }
            op[j * 64 + lane] = (uint16_t)pk;
        }
        #pragma unroll
        for (int off = 32; off > 0; off >>= 1) m = fmaxf(m, __shfl_down(m, off));
        if (lane == 0) scale[gw] = m;
    } else {
        const int r = gw - M_ROWS;
        // lane L quantizes elems [L*32, L*32+32) of row r -> one 16B chunk
        const float4* rp = (const float4*)(w + (size_t)r * K_IN + lane * 32);
        const float4* gp = (const float4*)(gamma + lane * 32);
        uint32_t pk[4] = {0, 0, 0, 0};
        #pragma unroll
        for (int j = 0; j < 8; j++) {
            float4 x = rp[j];
            float4 g = gp[j];
            float xs[4] = {x.x, x.y, x.z, x.w};
            float gs[4] = {g.x, g.y, g.z, g.w};
            #pragma unroll
            for (int c = 0; c < 4; c++) {
                int e = j * 4 + c;                 // elem index within chunk
                float s = (xs[c] > 0.f) ? 1.f : ((xs[c] < 0.f) ? -1.f : 0.f);
                pk[e >> 3] |= fp4_e2m1(s / gs[c]) << ((e & 7) * 4);
            }
        }
        uint4 v; v.x = pk[0]; v.y = pk[1]; v.z = pk[2]; v.w = pk[3];
        *(uint4*)(wqt + ((size_t)lane * N_OUT + r) * 16) = v;
    }
}

// ---------------------------------------------------------------------------
// MX-fp4 MFMA GEMM, A LDS DOUBLE-BUFFERED DMA, B DIRECT FROM L2.
// C[m,n] = sum_k Aq[m,k]*Wqt[k,n]. 128x128 block tile, BK=256 elems,
// 8 K-iters, ONE barrier per iter. Iter i: issue DMA(tile i+1)->buf[i+1&1],
// load B frags (global, LDS-independent), compute tile i from buf[i&1],
// barrier (drains DMA i+1 AFTER the full MFMA phase -> latency hidden;
// also licenses buf[i&1] overwrite at iter i+1... i+2).
// A: XOR chunk swizzle (phys = logical ^ (row&7)), source-side.
// B: coalesced 16-lane x 16B contiguous loads; Wqt = 2 MB, L2-resident.
// NOTE: (256,4) caps VGPR at 64 -> acc spills (R3, 2.5x slower);
// register-staged LDS dbuf loses on LDS-port pressure (R4); 2-barrier
// single-buffer exposes DMA latency every iter (R5/R6 ~32 us). (256,2).
#define BM   128
#define BN   128
#define BKBY 128   /* bytes of packed fp4 A per row per iter = 256 elems */
#define NIT  (KB4 / BKBY)   /* 8 */

__global__ __launch_bounds__(256, 2) void gemm_q(
    const uint8_t* __restrict__ Aq,
    const uint8_t* __restrict__ Wqt,
    const float* __restrict__ scale,
    const float* __restrict__ bias,
    const float* __restrict__ beta,
    float* __restrict__ out)
{
    __shared__ uint8_t As[2][BM * BKBY];   // 2 x 16 KB

    const int tid  = threadIdx.x;
    const int lane = tid & 63;
    const int wave = tid >> 6;

    const int row0 = blockIdx.x * BM;
    const int col0 = blockIdx.y * BN;

    const int wm = (wave >> 1) * 64;
    const int wn = (wave & 1)  * 64;

    // A staging: thread t (issue i) covers row i*32 + (t>>3), phys chunk t&7
    const int st_row = tid >> 3;                 // 0..31
    const int st_pc  = tid & 7;                  // physical 16B chunk
    const int st_gc  = st_pc ^ (st_row & 7);     // swizzled source chunk

    const uint8_t* gA = Aq + (size_t)(row0 + st_row) * KB4 + st_gc * 16;
    const int lOff = st_row * BKBY + st_pc * 16;

    f32x4 acc[4][4];
    #pragma unroll
    for (int i = 0; i < 4; i++) {
        #pragma unroll
        for (int j = 0; j < 4; j++) acc[i][j] = (f32x4)(0.f);
    }

    const int fr = lane & 15;            // fragment row (m) / col (n)
    const int g  = lane >> 4;            // k-chunk group (32 elems = 16 B)
    // A chunk offsets for kh-th half (chunk kh*4+g), XOR-swizzled per row
    const int offA0 = ((0 * 4 + g) ^ (fr & 7)) << 4;
    const int offA1 = ((1 * 4 + g) ^ (fr & 7)) << 4;

    // B: plane stride = one k-chunk of all N columns
    const size_t PS = (size_t)N_OUT * 16;        // 32 KB
    const uint8_t* gBt = Wqt + (size_t)(col0 + wn + fr) * 16 + (size_t)g * PS;

    // prologue: DMA tile 0 into buf 0
    #pragma unroll
    for (int i = 0; i < 4; i++)
        load_lds16(gA + (size_t)(i * 32) * KB4, &As[0][lOff + i * 32 * BKBY]);
    __syncthreads();

    #pragma unroll
    for (int it = 0; it < NIT; it++) {
        const int kb = it * BKBY;
        const uint8_t* curA = As[it & 1];

        if (it + 1 < NIT) {            // prefetch tile it+1 into idle buffer
            uint8_t* nA = &As[(it + 1) & 1][lOff];
            #pragma unroll
            for (int i = 0; i < 4; i++)
                load_lds16(gA + (size_t)(i * 32) * KB4 + kb + BKBY,
                           nA + i * 32 * BKBY);
        }

        const uint8_t* bp = gBt + (size_t)(kb >> 4) * PS;
        v4i b0[4], b1[4];
        #pragma unroll
        for (int ni = 0; ni < 4; ni++) {
            b0[ni] = *(const v4i*)(bp + ni * 256);
            b1[ni] = *(const v4i*)(bp + 4 * PS + ni * 256);
        }

        #pragma unroll
        for (int kh = 0; kh < 2; kh++) {
            const int offA = kh ? offA1 : offA0;
            v8i a[4];
            #pragma unroll
            for (int mi = 0; mi < 4; mi++) {
                v4i lo = *(const v4i*)(&curA[(wm + mi * 16 + fr) * BKBY] + offA);
                a[mi] = (v8i){lo.x, lo.y, lo.z, lo.w, 0, 0, 0, 0};
            }
            #pragma unroll
            for (int mi = 0; mi < 4; mi++) {
                #pragma unroll
                for (int ni = 0; ni < 4; ni++) {
                    v4i lb = kh ? b1[ni] : b0[ni];
                    v8i b = (v8i){lb.x, lb.y, lb.z, lb.w, 0, 0, 0, 0};
                    acc[mi][ni] = __builtin_amdgcn_mfma_scale_f32_16x16x128_f8f6f4(
                        a[mi], b, acc[mi][ni],
                        4 /*cbsz: A=fp4 e2m1*/, 4 /*blgp: B=fp4 e2m1*/,
                        0, 0x7F7F7F7F,   /* A scales = 1.0 */
                        0, 0x7F7F7F7F);  /* B scales = 1.0 */
                }
            }
        }
        __syncthreads();   // drains DMA(it+1) after full MFMA phase
    }

    // epilogue: C/D layout col=lane&15, row=(lane>>4)*4+reg
    const int ecol = lane & 15;
    const int erow = (lane >> 4) * 4;

    float bi[4], be[4];
    #pragma unroll
    for (int ni = 0; ni < 4; ni++) {
        int col = col0 + wn + ni * 16 + ecol;
        bi[ni] = bias[col];
        be[ni] = beta[col];
    }
    #pragma unroll
    for (int mi = 0; mi < 4; mi++) {
        int rbase = row0 + wm + mi * 16 + erow;
        float sc[4];
        #pragma unroll
        for (int r = 0; r < 4; r++) sc[r] = scale[rbase + r];
        #pragma unroll
        for (int ni = 0; ni < 4; ni++) {
            int col = col0 + wn + ni * 16 + ecol;
            float* op = out + (size_t)rbase * N_OUT + col;
            #pragma unroll
            for (int r = 0; r < 4; r++)
                op[(size_t)r * N_OUT] = (acc[mi][ni][r] * sc[r] + bi[ni]) * be[ni];
        }
    }
}

// ---------------------------------------------------------------------------
// Fallback (no workspace): correct but slow.
__global__ __launch_bounds__(256) void fallback_kernel(
    const float* __restrict__ in, const float* __restrict__ w,
    const float* __restrict__ bias, const float* __restrict__ gamma,
    const float* __restrict__ beta, float* __restrict__ out)
{
    __shared__ float s_sign[K_IN];
    __shared__ float sred[4];
    const int row = blockIdx.x;
    const int tid = threadIdx.x;
    float m = 0.f;
    for (int k = tid; k < K_IN; k += 256) {
        float x = in[(size_t)row * K_IN + k];
        m = fmaxf(m, fabsf(x));
        float s = (x > 0.f) ? 1.f : ((x < 0.f) ? -1.f : 0.f);
        s_sign[k] = s / gamma[k];
    }
    #pragma unroll
    for (int off = 32; off > 0; off >>= 1) m = fmaxf(m, __shfl_down(m, off));
    if ((tid & 63) == 0) sred[tid >> 6] = m;
    __syncthreads();
    float qs = fmaxf(fmaxf(sred[0], sred[1]), fmaxf(sred[2], sred[3]));
    for (int o = tid; o < N_OUT; o += 256) {
        const float* wr = w + (size_t)o * K_IN;
        float acc2 = 0.f;
        for (int k = 0; k < K_IN; k++) {
            float wv = wr[k];
            float ws_ = (wv > 0.f) ? 1.f : ((wv < 0.f) ? -1.f : 0.f);
            acc2 += s_sign[k] * ws_;
        }
        out[(size_t)row * N_OUT + o] = (acc2 * qs + bias[o]) * beta[o];
    }
}

// ---------------------------------------------------------------------------
extern "C" void kernel_launch(void* const* d_in, const int* in_sizes, int n_in,
                              void* d_out, int out_size, void* d_ws, size_t ws_size,
                              hipStream_t stream) {
    const float* input  = (const float*)d_in[0];
    const float* weight = (const float*)d_in[1];
    const float* bias   = (const float*)d_in[2];
    const float* gamma  = (const float*)d_in[3];
    const float* beta   = (const float*)d_in[4];
    float* out = (float*)d_out;

    const size_t aq_bytes = (size_t)M_ROWS * KB4;             // 8 MB
    const size_t wq_bytes = (size_t)N_OUT * KB4;              // 2 MB
    const size_t sc_bytes = (size_t)M_ROWS * sizeof(float);   // 32 KB

    if (ws_size >= aq_bytes + wq_bytes + sc_bytes) {
        uint8_t* aq    = (uint8_t*)d_ws;
        uint8_t* wqt   = (uint8_t*)d_ws + aq_bytes;
        float*   scale = (float*)((char*)d_ws + aq_bytes + wq_bytes);

        const int q_blocks = (M_ROWS + N_OUT) / 4;            // 2560 (4 waves/blk)
        quant_rows<<<q_blocks, 256, 0, stream>>>(
            input, weight, gamma, aq, wqt, scale);
        dim3 grid(M_ROWS / BM, N_OUT / BN);
        gemm_q<<<grid, 256, 0, stream>>>(aq, wqt, scale, bias, beta, out);
    } else {
        fallback_kernel<<<M_ROWS, 256, 0, stream>>>(input, weight, bias, gamma, beta, out);
    }
}